// Round 8
// baseline (109.618 us; speedup 1.0000x reference)
//
#include <hip/hip_runtime.h>

#define N_NODES 25000
#define N_EDGES 400000
#define IN_DIM 174
#define HID_DIM 128
#define OUT_DIM 64
#define MPAD 25088   // 196 * 128, GEMM M padded
#define BINCAP 64    // max degree capacity (Poisson mean 16)

using u32 = unsigned int;
typedef __attribute__((ext_vector_type(8))) short s16x8;
typedef __attribute__((ext_vector_type(4))) float f32x4;
typedef __attribute__((ext_vector_type(4))) u32 u32x4;

// ---------- bf16 helpers (RNE) ----------
__device__ __forceinline__ float bflo(u32 u) { u32 t = u << 16; return __builtin_bit_cast(float, t); }
__device__ __forceinline__ float bfhi(u32 u) { u32 t = u & 0xffff0000u; return __builtin_bit_cast(float, t); }
__device__ __forceinline__ u32 f2b(float f) {
    u32 u = __builtin_bit_cast(u32, f);
    return (u + 0x7fffu + ((u >> 16) & 1u)) >> 16;
}
__device__ __forceinline__ u32 packbf2(float a, float b) { return f2b(a) | (f2b(b) << 16); }

__device__ __forceinline__ void gload_lds16(const void* g, void* l) {
    __builtin_amdgcn_global_load_lds(
        (const __attribute__((address_space(1))) u32*)g,
        (__attribute__((address_space(3))) u32*)l, 16, 0, 0);
}

// ---------------- prep: weights->bf16 + zero degI (tiny) ----------------
#define WB1_CNT (256 * 96)
#define WB2_CNT (128 * 64)
#define PREP_TOT (WB1_CNT + WB2_CNT + N_NODES)

__global__ __launch_bounds__(256) void prep_w_kernel(
    const float* __restrict__ W1l, const float* __restrict__ W1r,
    const float* __restrict__ W2l, const float* __restrict__ W2r,
    u32* __restrict__ wb1, u32* __restrict__ wb2, int* __restrict__ degI) {
    int idx = blockIdx.x * blockDim.x + threadIdx.x;
    if (idx < WB1_CNT) {
        int nrow = idx / 96, d2 = idx - nrow * 96;
        const float* src = (nrow < 128) ? W1l + (size_t)nrow * IN_DIM
                                        : W1r + (size_t)(nrow - 128) * IN_DIM;
        float2 v = make_float2(0.f, 0.f);
        if (d2 < 87) v = ((const float2*)src)[d2];
        wb1[idx] = packbf2(v.x, v.y);
        return;
    }
    idx -= WB1_CNT;
    if (idx < WB2_CNT) {
        int nrow = idx >> 6, d2 = idx & 63;
        const float* src = (nrow < 64) ? W2l + (size_t)nrow * HID_DIM
                                       : W2r + (size_t)(nrow - 64) * HID_DIM;
        float2 v = ((const float2*)src)[d2];
        wb2[idx] = packbf2(v.x, v.y);
        return;
    }
    idx -= WB2_CNT;
    if (idx < N_NODES) degI[idx] = 0;
}

// ---------------- gemm1 (A = x fp32, converted in-kernel; B = wb1 gload_lds)
// ---------------- + fused edge binning (independent blocks) ----------------
#define G1_GEMM_BLOCKS 392
#define G1_EDGE_BLOCKS ((N_EDGES / 4 + 255) / 256)

__global__ __launch_bounds__(256) void gemm1_fused_kernel(
    const float* __restrict__ x, const ushort* __restrict__ wb1,
    ushort* __restrict__ y1n, ushort* __restrict__ y1r,
    const int* __restrict__ ei, int* __restrict__ degI, int* __restrict__ bins) {
    const int bid = blockIdx.x;
    const int tid = threadIdx.x;

    if (bid >= G1_GEMM_BLOCKS) {
        // ---- edge binning: 4 edges/thread ----
        int e4 = ((bid - G1_GEMM_BLOCKS) * 256 + tid) * 4;
        if (e4 < N_EDGES) {  // N_EDGES % 4 == 0
            int4 s = *(const int4*)(ei + e4);
            int4 t = *(const int4*)(ei + N_EDGES + e4);
            int p0 = atomicAdd(&degI[t.x], 1);
            if (p0 < BINCAP) bins[t.x * BINCAP + p0] = s.x;
            int p1 = atomicAdd(&degI[t.y], 1);
            if (p1 < BINCAP) bins[t.y * BINCAP + p1] = s.y;
            int p2 = atomicAdd(&degI[t.z], 1);
            if (p2 < BINCAP) bins[t.z * BINCAP + p2] = s.z;
            int p3 = atomicAdd(&degI[t.w], 1);
            if (p3 < BINCAP) bins[t.w * BINCAP + p3] = s.w;
        }
        return;
    }

    // ---- gemm tile (128x128, K=192) ----
    __shared__ ushort As[128 * 32];
    __shared__ ushort Bs[128 * 32];
    const int lane = tid & 63, w = tid >> 6;
    const int gy = bid / 196, gx = bid - gy * 196;
    const int m0 = gx * 128, n0 = gy * 128;
    const int wmo = (w >> 1) * 64, wno = (w & 1) * 64;
    const int arow = lane >> 2;          // gload_lds: 16 rows per 1KB wave-call
    const int achunk = (lane & 3) * 8;
    const int r4 = tid >> 2;             // reg-stage: row within 64-row half
    const int q  = tid & 3;              // 16B chunk within 32-elem slab
    const int fr = lane & 15, fo = (lane >> 4) * 8;

    f32x4 acc[4][4] = {};

    for (int kk = 0; kk < 192; kk += 32) {
        // B: async global->LDS (pre-converted bf16 weights)
        #pragma unroll
        for (int c = 0; c < 2; ++c) {
            int r = w * 32 + c * 16;
            gload_lds16(wb1 + (size_t)(n0 + r + arow) * 192 + kk + achunk, &Bs[r * 32]);
        }
        // A: x fp32 -> bf16 reg-staged (contiguous b128 writes, conflict-free)
        #pragma unroll
        for (int it = 0; it < 2; ++it) {
            int r = it * 64 + r4;
            int gm = m0 + r;
            u32x4 o;
            #pragma unroll
            for (int e = 0; e < 4; ++e) {
                int col = kk + q * 8 + e * 2;
                float2 v = make_float2(0.f, 0.f);
                if (gm < N_NODES && col < IN_DIM)
                    v = *(const float2*)(x + (size_t)gm * IN_DIM + col);
                o[e] = packbf2(v.x, v.y);
            }
            ((u32x4*)As)[r * 4 + q] = o;
        }
        __syncthreads();
        s16x8 af[4], bf[4];
        #pragma unroll
        for (int i = 0; i < 4; ++i) {
            af[i] = *(const s16x8*)&As[(wmo + i * 16 + fr) * 32 + fo];
            bf[i] = *(const s16x8*)&Bs[(wno + i * 16 + fr) * 32 + fo];
        }
        #pragma unroll
        for (int i = 0; i < 4; ++i)
            #pragma unroll
            for (int j = 0; j < 4; ++j)
                acc[i][j] = __builtin_amdgcn_mfma_f32_16x16x32_bf16(af[i], bf[j], acc[i][j], 0, 0, 0);
        __syncthreads();
    }

    const int cr = (lane >> 4) * 4, cc = lane & 15;
    #pragma unroll
    for (int i = 0; i < 4; ++i)
        #pragma unroll
        for (int r = 0; r < 4; ++r) {
            int row = m0 + wmo + i * 16 + cr + r;
            #pragma unroll
            for (int j = 0; j < 4; ++j) {
                int colg = n0 + wno + j * 16 + cc;
                ushort* Cp = (colg < 128) ? y1n : y1r;
                int c = colg & 127;
                Cp[(size_t)row * 128 + c] = (ushort)f2b(acc[i][j][r]);
            }
        }
}

// ---------------- agg1 fused into gemm2 -------------------------------------
// Per block (BM=64): gather-stage h1 rows (relu(mean(y1n)+y1r+b1)) directly
// into XOR-swizzled LDS [64][128] bf16, prefetch all of B (wb2) async, then a
// barrier-free 4-step MFMA loop. Each h1 row is consumed by exactly one block.
__global__ __launch_bounds__(256) void agg1gemm2_kernel(
    const u32* __restrict__ y1n, const u32* __restrict__ y1r,
    const int* __restrict__ degI, const int* __restrict__ bins,
    const float* __restrict__ b1, const ushort* __restrict__ wb2,
    ushort* __restrict__ y2n, ushort* __restrict__ y2r) {
    __shared__ u32 As2[64 * 64];          // 16KB: [64 rows][64 u32], swizzled
    __shared__ ushort Bs2[4][128 * 32];   // 32KB: all 4 K-steps of B
    const int tid = threadIdx.x, lane = tid & 63, w = tid >> 6;
    const int m0 = blockIdx.x * 64;
    const int arow = lane >> 2, achunk = (lane & 3) * 8;

    // prefetch B: 4 k-steps x 2 calls/wave (async, drained at the barrier)
    #pragma unroll
    for (int ks = 0; ks < 4; ++ks)
        #pragma unroll
        for (int c = 0; c < 2; ++c) {
            int r = w * 32 + c * 16;
            gload_lds16(wb2 + (size_t)(r + arow) * 128 + ks * 32 + achunk,
                        &Bs2[ks][r * 32]);
        }

    // gather-stage A: wave w handles rows w*16 .. w*16+15
    float2 bb = ((const float2*)b1)[lane];
    for (int t = 0; t < 16; ++t) {
        int rl = w * 16 + t;
        int n = m0 + rl;
        u32 val = 0;
        if (n < N_NODES) {
            int deg = degI[n];
            int d = min(deg, BINCAP);
            const int* bp = bins + n * BINCAP;
            float a0 = 0.f, a1 = 0.f;
            int j = 0;
            for (; j + 8 <= d; j += 8) {
                int4 sa = *(const int4*)(bp + j);
                int4 sb = *(const int4*)(bp + j + 4);
                u32 u0 = y1n[(size_t)sa.x * 64 + lane];
                u32 u1 = y1n[(size_t)sa.y * 64 + lane];
                u32 u2 = y1n[(size_t)sa.z * 64 + lane];
                u32 u3 = y1n[(size_t)sa.w * 64 + lane];
                u32 u4 = y1n[(size_t)sb.x * 64 + lane];
                u32 u5 = y1n[(size_t)sb.y * 64 + lane];
                u32 u6 = y1n[(size_t)sb.z * 64 + lane];
                u32 u7 = y1n[(size_t)sb.w * 64 + lane];
                a0 += bflo(u0) + bflo(u1) + bflo(u2) + bflo(u3)
                    + bflo(u4) + bflo(u5) + bflo(u6) + bflo(u7);
                a1 += bfhi(u0) + bfhi(u1) + bfhi(u2) + bfhi(u3)
                    + bfhi(u4) + bfhi(u5) + bfhi(u6) + bfhi(u7);
            }
            if (j + 4 <= d) {
                int4 s4 = *(const int4*)(bp + j);
                u32 u0 = y1n[(size_t)s4.x * 64 + lane];
                u32 u1 = y1n[(size_t)s4.y * 64 + lane];
                u32 u2 = y1n[(size_t)s4.z * 64 + lane];
                u32 u3 = y1n[(size_t)s4.w * 64 + lane];
                a0 += bflo(u0) + bflo(u1) + bflo(u2) + bflo(u3);
                a1 += bfhi(u0) + bfhi(u1) + bfhi(u2) + bfhi(u3);
                j += 4;
            }
            for (; j < d; ++j) {
                int s = bp[j];
                u32 u = y1n[(size_t)s * 64 + lane];
                a0 += bflo(u); a1 += bfhi(u);
            }
            float inv = 1.f / fmaxf((float)deg, 1.f);
            u32 ur = y1r[(size_t)n * 64 + lane];
            float v0 = fmaxf(a0 * inv + bflo(ur) + bb.x, 0.f);
            float v1 = fmaxf(a1 * inv + bfhi(ur) + bb.y, 0.f);
            val = packbf2(v0, v1);
        }
        // swizzled write: byte = (rl*256 + lane*4) ^ ((rl&7)<<4)
        u32 bidx = (((u32)(rl * 256 + lane * 4)) ^ (u32)((rl & 7) << 4)) >> 2;
        As2[bidx] = val;
    }
    __syncthreads();  // drains gload_lds (vmcnt) + As2 writes

    // barrier-free MFMA loop (LDS is read-only from here)
    const int wmo = (w >> 1) * 32, wno = (w & 1) * 64;
    const int fr = lane & 15, fo = (lane >> 4) * 8;
    f32x4 acc[2][4] = {};
    #pragma unroll
    for (int ks = 0; ks < 4; ++ks) {
        s16x8 af[2], bf[4];
        #pragma unroll
        for (int i = 0; i < 2; ++i) {
            int mr = wmo + i * 16 + fr;
            u32 byt = ((u32)(mr * 256 + (ks * 32 + fo) * 2)) ^ (u32)((mr & 7) << 4);
            af[i] = *(const s16x8*)((const char*)As2 + byt);
        }
        #pragma unroll
        for (int j = 0; j < 4; ++j)
            bf[j] = *(const s16x8*)&Bs2[ks][(wno + j * 16 + fr) * 32 + fo];
        #pragma unroll
        for (int i = 0; i < 2; ++i)
            #pragma unroll
            for (int j = 0; j < 4; ++j)
                acc[i][j] = __builtin_amdgcn_mfma_f32_16x16x32_bf16(af[i], bf[j], acc[i][j], 0, 0, 0);
    }

    const int cr = (lane >> 4) * 4, cc = lane & 15;
    #pragma unroll
    for (int i = 0; i < 2; ++i)
        #pragma unroll
        for (int r = 0; r < 4; ++r) {
            int row = m0 + wmo + i * 16 + cr + r;
            #pragma unroll
            for (int j = 0; j < 4; ++j) {
                int colg = wno + j * 16 + cc;
                ushort* Cp = (colg < 64) ? y2n : y2r;
                int c = colg & 63;
                Cp[(size_t)row * 64 + c] = (ushort)f2b(acc[i][j][r]);
            }
        }
}

// ---------------- agg2: out = mean_neigh(y2n) + y2r + b2 (fp32) ----------------
__global__ __launch_bounds__(256) void agg2_kernel(const u32* __restrict__ y2n,
                                                   const u32* __restrict__ y2r,
                                                   const int* __restrict__ degI,
                                                   const int* __restrict__ bins,
                                                   const float* __restrict__ b2,
                                                   float2* __restrict__ out) {
    int w = threadIdx.x >> 6, lane = threadIdx.x & 63;
    int half = lane >> 5, dd = lane & 31;
    int n = blockIdx.x * 4 + w;
    if (n >= N_NODES) return;
    int deg = degI[n];
    int d = min(deg, BINCAP);
    const int* bp = bins + n * BINCAP;
    float a0 = 0.f, a1 = 0.f;
    int j = 0;
    for (; j + 8 <= d; j += 8) {
        int s0 = bp[j + half],     s1 = bp[j + 2 + half];
        int s2 = bp[j + 4 + half], s3 = bp[j + 6 + half];
        u32 u0 = y2n[(size_t)s0 * 32 + dd];
        u32 u1 = y2n[(size_t)s1 * 32 + dd];
        u32 u2 = y2n[(size_t)s2 * 32 + dd];
        u32 u3 = y2n[(size_t)s3 * 32 + dd];
        a0 += bflo(u0) + bflo(u1) + bflo(u2) + bflo(u3);
        a1 += bfhi(u0) + bfhi(u1) + bfhi(u2) + bfhi(u3);
    }
    if (j + 4 <= d) {
        int s0 = bp[j + half], s1 = bp[j + 2 + half];
        u32 u0 = y2n[(size_t)s0 * 32 + dd];
        u32 u1 = y2n[(size_t)s1 * 32 + dd];
        a0 += bflo(u0) + bflo(u1);
        a1 += bfhi(u0) + bfhi(u1);
        j += 4;
    }
    if (j + 2 <= d) {
        int s = bp[j + half];
        u32 u = y2n[(size_t)s * 32 + dd];
        a0 += bflo(u); a1 += bfhi(u);
        j += 2;
    }
    if (j < d && half == 0) {
        int s = bp[j];
        u32 u = y2n[(size_t)s * 32 + dd];
        a0 += bflo(u); a1 += bfhi(u);
    }
    a0 += __shfl_xor(a0, 32, 64);
    a1 += __shfl_xor(a1, 32, 64);
    if (half == 0) {
        float inv = 1.f / fmaxf((float)deg, 1.f);
        u32 ur = y2r[(size_t)n * 32 + dd];
        float2 bb = ((const float2*)b2)[dd];
        float2 o;
        o.x = a0 * inv + bflo(ur) + bb.x;
        o.y = a1 * inv + bfhi(ur) + bb.y;
        out[(size_t)n * 32 + dd] = o;
    }
}

// ---------------- launch ----------------

extern "C" void kernel_launch(void* const* d_in, const int* in_sizes, int n_in,
                              void* d_out, int out_size, void* d_ws, size_t ws_size,
                              hipStream_t stream) {
    const float* x   = (const float*)d_in[0];
    const int*   ei  = (const int*)d_in[1];
    const float* W1l = (const float*)d_in[2];
    const float* b1  = (const float*)d_in[3];
    const float* W1r = (const float*)d_in[4];
    const float* W2l = (const float*)d_in[5];
    const float* b2  = (const float*)d_in[6];
    const float* W2r = (const float*)d_in[7];

    char* wp = (char*)d_ws;
    auto alloc = [&](size_t bytes) -> char* {
        char* p = wp;
        wp += (bytes + 255) & ~(size_t)255;
        return p;
    };
    int* degI = (int*)alloc((size_t)N_NODES * 4);
    int* bins = (int*)alloc((size_t)N_NODES * BINCAP * 4);
    u32* wb1  = (u32*)alloc((size_t)WB1_CNT * 4);
    u32* wb2  = (u32*)alloc((size_t)WB2_CNT * 4);
    u32* y1n  = (u32*)alloc((size_t)MPAD * 64 * 4);   // [MPAD][128] bf16 (neighbor half)
    u32* y1r  = (u32*)alloc((size_t)MPAD * 64 * 4);   // [MPAD][128] bf16 (root half)
    u32* y2n  = (u32*)alloc((size_t)MPAD * 32 * 4);   // [MPAD][64] bf16
    u32* y2r  = (u32*)alloc((size_t)MPAD * 32 * 4);

    prep_w_kernel<<<(PREP_TOT + 255) / 256, 256, 0, stream>>>(
        W1l, W1r, W2l, W2r, wb1, wb2, degI);
    gemm1_fused_kernel<<<G1_GEMM_BLOCKS + G1_EDGE_BLOCKS, 256, 0, stream>>>(
        x, (const ushort*)wb1, (ushort*)y1n, (ushort*)y1r, ei, degI, bins);
    agg1gemm2_kernel<<<392, 256, 0, stream>>>(
        y1n, y1r, degI, bins, b1, (const ushort*)wb2, (ushort*)y2n, (ushort*)y2r);
    agg2_kernel<<<(N_NODES + 3) / 4, 256, 0, stream>>>(
        y2n, y2r, degI, bins, b2, (float2*)d_out);
}

// Round 9
// 77.122 us; speedup vs baseline: 1.4214x; 1.4214x over previous
//
#include <hip/hip_runtime.h>

#define N_NODES 25000
#define N_EDGES 400000
#define IN_DIM 174
#define HID_DIM 128
#define OUT_DIM 64
#define MPAD 25088   // 196 * 128, GEMM M padded
#define BINCAP 64    // max degree capacity (Poisson mean 16; max ~45)

using u32 = unsigned int;
typedef __attribute__((ext_vector_type(8))) short s16x8;
typedef __attribute__((ext_vector_type(4))) float f32x4;
typedef __attribute__((ext_vector_type(4))) u32 u32x4;

// ---------- bf16 helpers (RNE) ----------
__device__ __forceinline__ float bflo(u32 u) { u32 t = u << 16; return __builtin_bit_cast(float, t); }
__device__ __forceinline__ float bfhi(u32 u) { u32 t = u & 0xffff0000u; return __builtin_bit_cast(float, t); }
__device__ __forceinline__ u32 f2b(float f) {
    u32 u = __builtin_bit_cast(u32, f);
    return (u + 0x7fffu + ((u >> 16) & 1u)) >> 16;
}
__device__ __forceinline__ u32 packbf2(float a, float b) { return f2b(a) | (f2b(b) << 16); }

__device__ __forceinline__ void gload_lds16(const void* g, void* l) {
    __builtin_amdgcn_global_load_lds(
        (const __attribute__((address_space(1))) u32*)g,
        (__attribute__((address_space(3))) u32*)l, 16, 0, 0);
}

// ---------------- prep: weights->bf16 + zero degI (tiny) ----------------
#define WB1_CNT (256 * 96)
#define WB2_CNT (128 * 64)
#define PREP_TOT (WB1_CNT + WB2_CNT + N_NODES)

__global__ __launch_bounds__(256) void prep_w_kernel(
    const float* __restrict__ W1l, const float* __restrict__ W1r,
    const float* __restrict__ W2l, const float* __restrict__ W2r,
    u32* __restrict__ wb1, u32* __restrict__ wb2, int* __restrict__ degI) {
    int idx = blockIdx.x * blockDim.x + threadIdx.x;
    if (idx < WB1_CNT) {
        int nrow = idx / 96, d2 = idx - nrow * 96;
        const float* src = (nrow < 128) ? W1l + (size_t)nrow * IN_DIM
                                        : W1r + (size_t)(nrow - 128) * IN_DIM;
        float2 v = make_float2(0.f, 0.f);
        if (d2 < 87) v = ((const float2*)src)[d2];
        wb1[idx] = packbf2(v.x, v.y);
        return;
    }
    idx -= WB1_CNT;
    if (idx < WB2_CNT) {
        int nrow = idx >> 6, d2 = idx & 63;
        const float* src = (nrow < 64) ? W2l + (size_t)nrow * HID_DIM
                                       : W2r + (size_t)(nrow - 64) * HID_DIM;
        float2 v = ((const float2*)src)[d2];
        wb2[idx] = packbf2(v.x, v.y);
        return;
    }
    idx -= WB2_CNT;
    if (idx < N_NODES) degI[idx] = 0;
}

// ---------------- gemm1 (A = x fp32, converted in-kernel; B = wb1 gload_lds)
// ---------------- + fused edge binning (independent blocks) ----------------
#define G1_GEMM_BLOCKS 392
#define G1_EDGE_BLOCKS ((N_EDGES / 4 + 255) / 256)

__global__ __launch_bounds__(256) void gemm1_fused_kernel(
    const float* __restrict__ x, const ushort* __restrict__ wb1,
    ushort* __restrict__ y1n, ushort* __restrict__ y1r,
    const int* __restrict__ ei, int* __restrict__ degI, int* __restrict__ bins) {
    const int bid = blockIdx.x;
    const int tid = threadIdx.x;

    if (bid >= G1_GEMM_BLOCKS) {
        // ---- edge binning: 4 edges/thread ----
        int e4 = ((bid - G1_GEMM_BLOCKS) * 256 + tid) * 4;
        if (e4 < N_EDGES) {  // N_EDGES % 4 == 0
            int4 s = *(const int4*)(ei + e4);
            int4 t = *(const int4*)(ei + N_EDGES + e4);
            int p0 = atomicAdd(&degI[t.x], 1);
            if (p0 < BINCAP) bins[t.x * BINCAP + p0] = s.x;
            int p1 = atomicAdd(&degI[t.y], 1);
            if (p1 < BINCAP) bins[t.y * BINCAP + p1] = s.y;
            int p2 = atomicAdd(&degI[t.z], 1);
            if (p2 < BINCAP) bins[t.z * BINCAP + p2] = s.z;
            int p3 = atomicAdd(&degI[t.w], 1);
            if (p3 < BINCAP) bins[t.w * BINCAP + p3] = s.w;
        }
        return;
    }

    // ---- gemm tile (128x128, K=192) ----
    __shared__ ushort As[128 * 32];
    __shared__ ushort Bs[128 * 32];
    const int lane = tid & 63, w = tid >> 6;
    const int gy = bid / 196, gx = bid - gy * 196;
    const int m0 = gx * 128, n0 = gy * 128;
    const int wmo = (w >> 1) * 64, wno = (w & 1) * 64;
    const int arow = lane >> 2;          // gload_lds: 16 rows per 1KB wave-call
    const int achunk = (lane & 3) * 8;
    const int r4 = tid >> 2;             // reg-stage: row within 64-row half
    const int q  = tid & 3;              // 16B chunk within 32-elem slab
    const int fr = lane & 15, fo = (lane >> 4) * 8;
    const bool mfull = (gx != 195);      // only last m-tile has rows >= N_NODES

    f32x4 acc[4][4] = {};

    for (int kk = 0; kk < 192; kk += 32) {
        // B: async global->LDS (pre-converted bf16 weights)
        #pragma unroll
        for (int c = 0; c < 2; ++c) {
            int r = w * 32 + c * 16;
            gload_lds16(wb1 + (size_t)(n0 + r + arow) * 192 + kk + achunk, &Bs[r * 32]);
        }
        // A: x fp32 -> bf16 reg-staged (bounds checks hoisted to uniform flags)
        #pragma unroll
        for (int it = 0; it < 2; ++it) {
            int r = it * 64 + r4;
            int gm = m0 + r;
            u32x4 o;
            if (mfull || gm < N_NODES) {
                const float* xr = x + (size_t)gm * IN_DIM + kk + q * 8;
                if (kk < 160) {  // col max = kk+30 <= 158 < 174: no col check
                    #pragma unroll
                    for (int e = 0; e < 4; ++e) {
                        float2 v = ((const float2*)xr)[e];
                        o[e] = packbf2(v.x, v.y);
                    }
                } else {         // kk=160: cols 160..190, valid < 174
                    #pragma unroll
                    for (int e = 0; e < 4; ++e) {
                        int col = kk + q * 8 + e * 2;
                        float2 v = make_float2(0.f, 0.f);
                        if (col < IN_DIM) v = ((const float2*)xr)[e];
                        o[e] = packbf2(v.x, v.y);
                    }
                }
            } else {
                o[0] = 0u; o[1] = 0u; o[2] = 0u; o[3] = 0u;
            }
            ((u32x4*)As)[r * 4 + q] = o;
        }
        __syncthreads();
        s16x8 af[4], bf[4];
        #pragma unroll
        for (int i = 0; i < 4; ++i) {
            af[i] = *(const s16x8*)&As[(wmo + i * 16 + fr) * 32 + fo];
            bf[i] = *(const s16x8*)&Bs[(wno + i * 16 + fr) * 32 + fo];
        }
        #pragma unroll
        for (int i = 0; i < 4; ++i)
            #pragma unroll
            for (int j = 0; j < 4; ++j)
                acc[i][j] = __builtin_amdgcn_mfma_f32_16x16x32_bf16(af[i], bf[j], acc[i][j], 0, 0, 0);
        __syncthreads();
    }

    const int cr = (lane >> 4) * 4, cc = lane & 15;
    #pragma unroll
    for (int i = 0; i < 4; ++i)
        #pragma unroll
        for (int r = 0; r < 4; ++r) {
            int row = m0 + wmo + i * 16 + cr + r;
            #pragma unroll
            for (int j = 0; j < 4; ++j) {
                int colg = n0 + wno + j * 16 + cc;
                ushort* Cp = (colg < 128) ? y1n : y1r;
                int c = colg & 127;
                Cp[(size_t)row * 128 + c] = (ushort)f2b(acc[i][j][r]);
            }
        }
}

// ---------------- gemm2: A = h1 bf16 (gload_lds), B = wb2 (gload_lds) -------
// BM=64, K=128, N=128 (cols 0..63 -> y2n, 64..127 -> y2r). grid 392.
__global__ __launch_bounds__(256) void gemm2_kernel(
    const ushort* __restrict__ h1, const ushort* __restrict__ wb2,
    ushort* __restrict__ y2n, ushort* __restrict__ y2r) {
    __shared__ ushort As[64 * 32];
    __shared__ ushort Bs[128 * 32];
    const int tid = threadIdx.x;
    const int lane = tid & 63, w = tid >> 6;
    const int m0 = blockIdx.x * 64;
    const int wmo = (w >> 1) * 32, wno = (w & 1) * 64;
    const int arow = lane >> 2;
    const int achunk = (lane & 3) * 8;
    const int fr = lane & 15, fo = (lane >> 4) * 8;

    f32x4 acc[2][4] = {};

    for (int kk = 0; kk < 128; kk += 32) {
        // A: h1 bf16 (pad rows hold finite garbage; pad outputs never read)
        {
            int r = w * 16;
            gload_lds16(h1 + (size_t)(m0 + r + arow) * 128 + kk + achunk, &As[r * 32]);
        }
        // B: wb2 bf16
        #pragma unroll
        for (int c = 0; c < 2; ++c) {
            int r = w * 32 + c * 16;
            gload_lds16(wb2 + (size_t)(r + arow) * 128 + kk + achunk, &Bs[r * 32]);
        }
        __syncthreads();
        s16x8 af[2], bf[4];
        #pragma unroll
        for (int i = 0; i < 2; ++i)
            af[i] = *(const s16x8*)&As[(wmo + i * 16 + fr) * 32 + fo];
        #pragma unroll
        for (int j = 0; j < 4; ++j)
            bf[j] = *(const s16x8*)&Bs[(wno + j * 16 + fr) * 32 + fo];
        #pragma unroll
        for (int i = 0; i < 2; ++i)
            #pragma unroll
            for (int j = 0; j < 4; ++j)
                acc[i][j] = __builtin_amdgcn_mfma_f32_16x16x32_bf16(af[i], bf[j], acc[i][j], 0, 0, 0);
        __syncthreads();
    }

    const int cr = (lane >> 4) * 4, cc = lane & 15;
    #pragma unroll
    for (int i = 0; i < 2; ++i)
        #pragma unroll
        for (int r = 0; r < 4; ++r) {
            int row = m0 + wmo + i * 16 + cr + r;
            #pragma unroll
            for (int j = 0; j < 4; ++j) {
                int colg = wno + j * 16 + cc;
                ushort* Cp = (colg < 64) ? y2n : y2r;
                int c = colg & 63;
                Cp[(size_t)row * 64 + c] = (ushort)f2b(acc[i][j][r]);
            }
        }
}

// ---------------- agg1: h1 = relu(mean_neigh(y1n) + y1r + b1), MLP16 --------
__global__ __launch_bounds__(256) void agg1_kernel(const u32* __restrict__ y1n,
                                                   const u32* __restrict__ y1r,
                                                   const int* __restrict__ degI,
                                                   const int* __restrict__ bins,
                                                   const float* __restrict__ b1,
                                                   u32* __restrict__ h1) {
    int w = threadIdx.x >> 6, lane = threadIdx.x & 63;
    int n = blockIdx.x * 4 + w;
    if (n >= N_NODES) return;
    int deg = degI[n];
    int d = min(deg, BINCAP);
    const int* bp = bins + n * BINCAP;
    float a0 = 0.f, a1 = 0.f;
    int j = 0;
    for (; j + 16 <= d; j += 16) {
        int4 sa = *(const int4*)(bp + j);
        int4 sb = *(const int4*)(bp + j + 4);
        int4 sc = *(const int4*)(bp + j + 8);
        int4 sd = *(const int4*)(bp + j + 12);
        u32 u0 = y1n[(size_t)sa.x * 64 + lane];
        u32 u1 = y1n[(size_t)sa.y * 64 + lane];
        u32 u2 = y1n[(size_t)sa.z * 64 + lane];
        u32 u3 = y1n[(size_t)sa.w * 64 + lane];
        u32 u4 = y1n[(size_t)sb.x * 64 + lane];
        u32 u5 = y1n[(size_t)sb.y * 64 + lane];
        u32 u6 = y1n[(size_t)sb.z * 64 + lane];
        u32 u7 = y1n[(size_t)sb.w * 64 + lane];
        u32 u8 = y1n[(size_t)sc.x * 64 + lane];
        u32 u9 = y1n[(size_t)sc.y * 64 + lane];
        u32 ua = y1n[(size_t)sc.z * 64 + lane];
        u32 ub = y1n[(size_t)sc.w * 64 + lane];
        u32 uc = y1n[(size_t)sd.x * 64 + lane];
        u32 ud = y1n[(size_t)sd.y * 64 + lane];
        u32 ue = y1n[(size_t)sd.z * 64 + lane];
        u32 uf = y1n[(size_t)sd.w * 64 + lane];
        a0 += bflo(u0) + bflo(u1) + bflo(u2) + bflo(u3)
            + bflo(u4) + bflo(u5) + bflo(u6) + bflo(u7)
            + bflo(u8) + bflo(u9) + bflo(ua) + bflo(ub)
            + bflo(uc) + bflo(ud) + bflo(ue) + bflo(uf);
        a1 += bfhi(u0) + bfhi(u1) + bfhi(u2) + bfhi(u3)
            + bfhi(u4) + bfhi(u5) + bfhi(u6) + bfhi(u7)
            + bfhi(u8) + bfhi(u9) + bfhi(ua) + bfhi(ub)
            + bfhi(uc) + bfhi(ud) + bfhi(ue) + bfhi(uf);
    }
    if (j + 8 <= d) {
        int4 sa = *(const int4*)(bp + j);
        int4 sb = *(const int4*)(bp + j + 4);
        u32 u0 = y1n[(size_t)sa.x * 64 + lane];
        u32 u1 = y1n[(size_t)sa.y * 64 + lane];
        u32 u2 = y1n[(size_t)sa.z * 64 + lane];
        u32 u3 = y1n[(size_t)sa.w * 64 + lane];
        u32 u4 = y1n[(size_t)sb.x * 64 + lane];
        u32 u5 = y1n[(size_t)sb.y * 64 + lane];
        u32 u6 = y1n[(size_t)sb.z * 64 + lane];
        u32 u7 = y1n[(size_t)sb.w * 64 + lane];
        a0 += bflo(u0) + bflo(u1) + bflo(u2) + bflo(u3)
            + bflo(u4) + bflo(u5) + bflo(u6) + bflo(u7);
        a1 += bfhi(u0) + bfhi(u1) + bfhi(u2) + bfhi(u3)
            + bfhi(u4) + bfhi(u5) + bfhi(u6) + bfhi(u7);
        j += 8;
    }
    if (j + 4 <= d) {
        int4 s4 = *(const int4*)(bp + j);
        u32 u0 = y1n[(size_t)s4.x * 64 + lane];
        u32 u1 = y1n[(size_t)s4.y * 64 + lane];
        u32 u2 = y1n[(size_t)s4.z * 64 + lane];
        u32 u3 = y1n[(size_t)s4.w * 64 + lane];
        a0 += bflo(u0) + bflo(u1) + bflo(u2) + bflo(u3);
        a1 += bfhi(u0) + bfhi(u1) + bfhi(u2) + bfhi(u3);
        j += 4;
    }
    for (; j < d; ++j) {
        int s = bp[j];
        u32 u = y1n[(size_t)s * 64 + lane];
        a0 += bflo(u); a1 += bfhi(u);
    }
    float inv = 1.f / fmaxf((float)deg, 1.f);
    u32 ur = y1r[(size_t)n * 64 + lane];
    float2 bb = ((const float2*)b1)[lane];
    float v0 = fmaxf(a0 * inv + bflo(ur) + bb.x, 0.f);
    float v1 = fmaxf(a1 * inv + bfhi(ur) + bb.y, 0.f);
    h1[(size_t)n * 64 + lane] = packbf2(v0, v1);
}

// ---------------- agg2: out = mean_neigh(y2n) + y2r + b2 (fp32), MLP16 ------
__global__ __launch_bounds__(256) void agg2_kernel(const u32* __restrict__ y2n,
                                                   const u32* __restrict__ y2r,
                                                   const int* __restrict__ degI,
                                                   const int* __restrict__ bins,
                                                   const float* __restrict__ b2,
                                                   float2* __restrict__ out) {
    int w = threadIdx.x >> 6, lane = threadIdx.x & 63;
    int half = lane >> 5, dd = lane & 31;
    int n = blockIdx.x * 4 + w;
    if (n >= N_NODES) return;
    int deg = degI[n];
    int d = min(deg, BINCAP);
    const int* bp = bins + n * BINCAP;
    float a0 = 0.f, a1 = 0.f;
    int j = 0;
    for (; j + 16 <= d; j += 16) {
        int s0 = bp[j + half],      s1 = bp[j + 2 + half];
        int s2 = bp[j + 4 + half],  s3 = bp[j + 6 + half];
        int s4 = bp[j + 8 + half],  s5 = bp[j + 10 + half];
        int s6 = bp[j + 12 + half], s7 = bp[j + 14 + half];
        u32 u0 = y2n[(size_t)s0 * 32 + dd];
        u32 u1 = y2n[(size_t)s1 * 32 + dd];
        u32 u2 = y2n[(size_t)s2 * 32 + dd];
        u32 u3 = y2n[(size_t)s3 * 32 + dd];
        u32 u4 = y2n[(size_t)s4 * 32 + dd];
        u32 u5 = y2n[(size_t)s5 * 32 + dd];
        u32 u6 = y2n[(size_t)s6 * 32 + dd];
        u32 u7 = y2n[(size_t)s7 * 32 + dd];
        a0 += bflo(u0) + bflo(u1) + bflo(u2) + bflo(u3)
            + bflo(u4) + bflo(u5) + bflo(u6) + bflo(u7);
        a1 += bfhi(u0) + bfhi(u1) + bfhi(u2) + bfhi(u3)
            + bfhi(u4) + bfhi(u5) + bfhi(u6) + bfhi(u7);
    }
    if (j + 8 <= d) {
        int s0 = bp[j + half],     s1 = bp[j + 2 + half];
        int s2 = bp[j + 4 + half], s3 = bp[j + 6 + half];
        u32 u0 = y2n[(size_t)s0 * 32 + dd];
        u32 u1 = y2n[(size_t)s1 * 32 + dd];
        u32 u2 = y2n[(size_t)s2 * 32 + dd];
        u32 u3 = y2n[(size_t)s3 * 32 + dd];
        a0 += bflo(u0) + bflo(u1) + bflo(u2) + bflo(u3);
        a1 += bfhi(u0) + bfhi(u1) + bfhi(u2) + bfhi(u3);
        j += 8;
    }
    if (j + 4 <= d) {
        int s0 = bp[j + half], s1 = bp[j + 2 + half];
        u32 u0 = y2n[(size_t)s0 * 32 + dd];
        u32 u1 = y2n[(size_t)s1 * 32 + dd];
        a0 += bflo(u0) + bflo(u1);
        a1 += bfhi(u0) + bfhi(u1);
        j += 4;
    }
    if (j + 2 <= d) {
        int s = bp[j + half];
        u32 u = y2n[(size_t)s * 32 + dd];
        a0 += bflo(u); a1 += bfhi(u);
        j += 2;
    }
    if (j < d && half == 0) {
        int s = bp[j];
        u32 u = y2n[(size_t)s * 32 + dd];
        a0 += bflo(u); a1 += bfhi(u);
    }
    a0 += __shfl_xor(a0, 32, 64);
    a1 += __shfl_xor(a1, 32, 64);
    if (half == 0) {
        float inv = 1.f / fmaxf((float)deg, 1.f);
        u32 ur = y2r[(size_t)n * 32 + dd];
        float2 bb = ((const float2*)b2)[dd];
        float2 o;
        o.x = a0 * inv + bflo(ur) + bb.x;
        o.y = a1 * inv + bfhi(ur) + bb.y;
        out[(size_t)n * 32 + dd] = o;
    }
}

// ---------------- launch ----------------

extern "C" void kernel_launch(void* const* d_in, const int* in_sizes, int n_in,
                              void* d_out, int out_size, void* d_ws, size_t ws_size,
                              hipStream_t stream) {
    const float* x   = (const float*)d_in[0];
    const int*   ei  = (const int*)d_in[1];
    const float* W1l = (const float*)d_in[2];
    const float* b1  = (const float*)d_in[3];
    const float* W1r = (const float*)d_in[4];
    const float* W2l = (const float*)d_in[5];
    const float* b2  = (const float*)d_in[6];
    const float* W2r = (const float*)d_in[7];

    char* wp = (char*)d_ws;
    auto alloc = [&](size_t bytes) -> char* {
        char* p = wp;
        wp += (bytes + 255) & ~(size_t)255;
        return p;
    };
    int* degI = (int*)alloc((size_t)N_NODES * 4);
    int* bins = (int*)alloc((size_t)N_NODES * BINCAP * 4);
    u32* wb1  = (u32*)alloc((size_t)WB1_CNT * 4);
    u32* wb2  = (u32*)alloc((size_t)WB2_CNT * 4);
    u32* y1n  = (u32*)alloc((size_t)MPAD * 64 * 4);   // [MPAD][128] bf16 (neighbor half)
    u32* y1r  = (u32*)alloc((size_t)MPAD * 64 * 4);   // [MPAD][128] bf16 (root half)
    u32* h1   = (u32*)alloc((size_t)MPAD * 64 * 4);   // [MPAD][128] bf16
    u32* y2n  = (u32*)alloc((size_t)MPAD * 32 * 4);   // [MPAD][64] bf16
    u32* y2r  = (u32*)alloc((size_t)MPAD * 32 * 4);

    prep_w_kernel<<<(PREP_TOT + 255) / 256, 256, 0, stream>>>(
        W1l, W1r, W2l, W2r, wb1, wb2, degI);
    gemm1_fused_kernel<<<G1_GEMM_BLOCKS + G1_EDGE_BLOCKS, 256, 0, stream>>>(
        x, (const ushort*)wb1, (ushort*)y1n, (ushort*)y1r, ei, degI, bins);
    agg1_kernel<<<(N_NODES + 3) / 4, 256, 0, stream>>>(
        y1n, y1r, degI, bins, b1, h1);
    gemm2_kernel<<<392, 256, 0, stream>>>(
        (const ushort*)h1, (const ushort*)wb2, (ushort*)y2n, (ushort*)y2r);
    agg2_kernel<<<(N_NODES + 3) / 4, 256, 0, stream>>>(
        y2n, y2r, degI, bins, b2, (float2*)d_out);
}

// Round 10
// 73.838 us; speedup vs baseline: 1.4846x; 1.0445x over previous
//
#include <hip/hip_runtime.h>

#define N_NODES 25000
#define N_EDGES 400000
#define IN_DIM 174
#define HID_DIM 128
#define OUT_DIM 64
#define MPAD 25088   // 392 * 64, GEMM M padded
#define BINCAP 64    // max degree capacity (Poisson mean 16; max ~45)

using u32 = unsigned int;
typedef __attribute__((ext_vector_type(8))) short s16x8;
typedef __attribute__((ext_vector_type(4))) float f32x4;
typedef __attribute__((ext_vector_type(4))) u32 u32x4;

// ---------- bf16 helpers (RNE) ----------
__device__ __forceinline__ float bflo(u32 u) { u32 t = u << 16; return __builtin_bit_cast(float, t); }
__device__ __forceinline__ float bfhi(u32 u) { u32 t = u & 0xffff0000u; return __builtin_bit_cast(float, t); }
__device__ __forceinline__ u32 f2b(float f) {
    u32 u = __builtin_bit_cast(u32, f);
    return (u + 0x7fffu + ((u >> 16) & 1u)) >> 16;
}
__device__ __forceinline__ u32 packbf2(float a, float b) { return f2b(a) | (f2b(b) << 16); }

__device__ __forceinline__ void gload_lds16(const void* g, void* l) {
    __builtin_amdgcn_global_load_lds(
        (const __attribute__((address_space(1))) u32*)g,
        (__attribute__((address_space(3))) u32*)l, 16, 0, 0);
}

// ---------------- prep: weights->bf16 + zero degI (tiny) ----------------
#define WB1_CNT (256 * 96)
#define WB2_CNT (128 * 64)
#define PREP_TOT (WB1_CNT + WB2_CNT + N_NODES)

__global__ __launch_bounds__(256) void prep_w_kernel(
    const float* __restrict__ W1l, const float* __restrict__ W1r,
    const float* __restrict__ W2l, const float* __restrict__ W2r,
    u32* __restrict__ wb1, u32* __restrict__ wb2, int* __restrict__ degI) {
    int idx = blockIdx.x * blockDim.x + threadIdx.x;
    if (idx < WB1_CNT) {
        int nrow = idx / 96, d2 = idx - nrow * 96;
        const float* src = (nrow < 128) ? W1l + (size_t)nrow * IN_DIM
                                        : W1r + (size_t)(nrow - 128) * IN_DIM;
        float2 v = make_float2(0.f, 0.f);
        if (d2 < 87) v = ((const float2*)src)[d2];
        wb1[idx] = packbf2(v.x, v.y);
        return;
    }
    idx -= WB1_CNT;
    if (idx < WB2_CNT) {
        int nrow = idx >> 6, d2 = idx & 63;
        const float* src = (nrow < 64) ? W2l + (size_t)nrow * HID_DIM
                                       : W2r + (size_t)(nrow - 64) * HID_DIM;
        float2 v = ((const float2*)src)[d2];
        wb2[idx] = packbf2(v.x, v.y);
        return;
    }
    idx -= WB2_CNT;
    if (idx < N_NODES) degI[idx] = 0;
}

// ---------------- gemm1: BM=64 x BN=256 single-pass (A converted once)
// ---------------- + fused edge binning (independent blocks) ----------------
#define G1_GEMM_BLOCKS 392                         // MPAD / 64
#define G1_EDGE_BLOCKS ((N_EDGES / 4 + 255) / 256) // 391

__global__ __launch_bounds__(256) void gemm1_fused_kernel(
    const float* __restrict__ x, const ushort* __restrict__ wb1,
    ushort* __restrict__ y1n, ushort* __restrict__ y1r,
    const int* __restrict__ ei, int* __restrict__ degI, int* __restrict__ bins) {
    const int bid = blockIdx.x;
    const int tid = threadIdx.x;

    if (bid >= G1_GEMM_BLOCKS) {
        // ---- edge binning: 4 edges/thread ----
        int e4 = ((bid - G1_GEMM_BLOCKS) * 256 + tid) * 4;
        if (e4 < N_EDGES) {  // N_EDGES % 4 == 0
            int4 s = *(const int4*)(ei + e4);
            int4 t = *(const int4*)(ei + N_EDGES + e4);
            int p0 = atomicAdd(&degI[t.x], 1);
            if (p0 < BINCAP) bins[t.x * BINCAP + p0] = s.x;
            int p1 = atomicAdd(&degI[t.y], 1);
            if (p1 < BINCAP) bins[t.y * BINCAP + p1] = s.y;
            int p2 = atomicAdd(&degI[t.z], 1);
            if (p2 < BINCAP) bins[t.z * BINCAP + p2] = s.z;
            int p3 = atomicAdd(&degI[t.w], 1);
            if (p3 < BINCAP) bins[t.w * BINCAP + p3] = s.w;
        }
        return;
    }

    // ---- gemm tile (64 x 256, K=192): each x row staged/converted exactly once ----
    __shared__ ushort As[64 * 32];
    __shared__ ushort Bs[256 * 32];
    const int lane = tid & 63, w = tid >> 6;
    const int m0 = bid * 64;
    const int wmo = (w >> 1) * 32;        // wave m-offset (2 halves of 32 rows)
    const int wno = (w & 1) * 128;        // wave n-offset (2 halves of 128 cols)
    const int arow = lane >> 2;           // gload_lds: 16 rows per 1KB wave-call
    const int achunk = (lane & 3) * 8;
    const int r4 = tid >> 2;              // A reg-stage: row 0..63
    const int q  = tid & 3;               // 16B chunk within 32-elem slab
    const int fr = lane & 15, fo = (lane >> 4) * 8;
    const bool mfull = (bid < 390);       // blocks 390/391 contain rows >= N_NODES

    f32x4 acc[2][8] = {};

    for (int kk = 0; kk < 192; kk += 32) {
        // B: async global->LDS (pre-converted bf16 weights), 256 rows = 4 calls/wave
        #pragma unroll
        for (int c = 0; c < 4; ++c) {
            int r = w * 64 + c * 16;
            gload_lds16(wb1 + (size_t)(r + arow) * 192 + kk + achunk, &Bs[r * 32]);
        }
        // A: x fp32 -> bf16 reg-staged (bounds checks hoisted to uniform flags)
        {
            int gm = m0 + r4;
            u32x4 o;
            if (mfull || gm < N_NODES) {
                const float* xr = x + (size_t)gm * IN_DIM + kk + q * 8;
                if (kk < 160) {  // col max = kk+30 <= 158 < 174: no col check
                    #pragma unroll
                    for (int e = 0; e < 4; ++e) {
                        float2 v = ((const float2*)xr)[e];
                        o[e] = packbf2(v.x, v.y);
                    }
                } else {         // kk=160: cols 160..190, valid < 174
                    #pragma unroll
                    for (int e = 0; e < 4; ++e) {
                        int col = kk + q * 8 + e * 2;
                        float2 v = make_float2(0.f, 0.f);
                        if (col < IN_DIM) v = ((const float2*)xr)[e];
                        o[e] = packbf2(v.x, v.y);
                    }
                }
            } else {
                o[0] = 0u; o[1] = 0u; o[2] = 0u; o[3] = 0u;
            }
            ((u32x4*)As)[r4 * 4 + q] = o;
        }
        __syncthreads();
        s16x8 af[2], bf[8];
        #pragma unroll
        for (int i = 0; i < 2; ++i)
            af[i] = *(const s16x8*)&As[(wmo + i * 16 + fr) * 32 + fo];
        #pragma unroll
        for (int j = 0; j < 8; ++j)
            bf[j] = *(const s16x8*)&Bs[(wno + j * 16 + fr) * 32 + fo];
        #pragma unroll
        for (int i = 0; i < 2; ++i)
            #pragma unroll
            for (int j = 0; j < 8; ++j)
                acc[i][j] = __builtin_amdgcn_mfma_f32_16x16x32_bf16(af[i], bf[j], acc[i][j], 0, 0, 0);
        __syncthreads();
    }

    const int cr = (lane >> 4) * 4, cc = lane & 15;
    #pragma unroll
    for (int i = 0; i < 2; ++i)
        #pragma unroll
        for (int r = 0; r < 4; ++r) {
            int row = m0 + wmo + i * 16 + cr + r;
            #pragma unroll
            for (int j = 0; j < 8; ++j) {
                int colg = wno + j * 16 + cc;          // 0..255
                ushort* Cp = (colg < 128) ? y1n : y1r;
                int c = colg & 127;
                Cp[(size_t)row * 128 + c] = (ushort)f2b(acc[i][j][r]);
            }
        }
}

// ---------------- gemm2: A = h1 bf16 (gload_lds), B = wb2 (gload_lds) -------
// BM=64, K=128, N=128 (cols 0..63 -> y2n, 64..127 -> y2r). grid 392.
__global__ __launch_bounds__(256) void gemm2_kernel(
    const ushort* __restrict__ h1, const ushort* __restrict__ wb2,
    ushort* __restrict__ y2n, ushort* __restrict__ y2r) {
    __shared__ ushort As[64 * 32];
    __shared__ ushort Bs[128 * 32];
    const int tid = threadIdx.x;
    const int lane = tid & 63, w = tid >> 6;
    const int m0 = blockIdx.x * 64;
    const int wmo = (w >> 1) * 32, wno = (w & 1) * 64;
    const int arow = lane >> 2;
    const int achunk = (lane & 3) * 8;
    const int fr = lane & 15, fo = (lane >> 4) * 8;

    f32x4 acc[2][4] = {};

    for (int kk = 0; kk < 128; kk += 32) {
        // A: h1 bf16 (pad rows hold finite garbage; pad outputs never read)
        {
            int r = w * 16;
            gload_lds16(h1 + (size_t)(m0 + r + arow) * 128 + kk + achunk, &As[r * 32]);
        }
        // B: wb2 bf16
        #pragma unroll
        for (int c = 0; c < 2; ++c) {
            int r = w * 32 + c * 16;
            gload_lds16(wb2 + (size_t)(r + arow) * 128 + kk + achunk, &Bs[r * 32]);
        }
        __syncthreads();
        s16x8 af[2], bf[4];
        #pragma unroll
        for (int i = 0; i < 2; ++i)
            af[i] = *(const s16x8*)&As[(wmo + i * 16 + fr) * 32 + fo];
        #pragma unroll
        for (int j = 0; j < 4; ++j)
            bf[j] = *(const s16x8*)&Bs[(wno + j * 16 + fr) * 32 + fo];
        #pragma unroll
        for (int i = 0; i < 2; ++i)
            #pragma unroll
            for (int j = 0; j < 4; ++j)
                acc[i][j] = __builtin_amdgcn_mfma_f32_16x16x32_bf16(af[i], bf[j], acc[i][j], 0, 0, 0);
        __syncthreads();
    }

    const int cr = (lane >> 4) * 4, cc = lane & 15;
    #pragma unroll
    for (int i = 0; i < 2; ++i)
        #pragma unroll
        for (int r = 0; r < 4; ++r) {
            int row = m0 + wmo + i * 16 + cr + r;
            #pragma unroll
            for (int j = 0; j < 4; ++j) {
                int colg = wno + j * 16 + cc;
                ushort* Cp = (colg < 64) ? y2n : y2r;
                int c = colg & 63;
                Cp[(size_t)row * 64 + c] = (ushort)f2b(acc[i][j][r]);
            }
        }
}

// ---------------- agg1: h1 = relu(mean_neigh(y1n) + y1r + b1), MLP16 --------
__global__ __launch_bounds__(256) void agg1_kernel(const u32* __restrict__ y1n,
                                                   const u32* __restrict__ y1r,
                                                   const int* __restrict__ degI,
                                                   const int* __restrict__ bins,
                                                   const float* __restrict__ b1,
                                                   u32* __restrict__ h1) {
    int w = threadIdx.x >> 6, lane = threadIdx.x & 63;
    int n = blockIdx.x * 4 + w;
    if (n >= N_NODES) return;
    int deg = degI[n];
    int d = min(deg, BINCAP);
    const int* bp = bins + n * BINCAP;
    float a0 = 0.f, a1 = 0.f;
    int j = 0;
    for (; j + 16 <= d; j += 16) {
        int4 sa = *(const int4*)(bp + j);
        int4 sb = *(const int4*)(bp + j + 4);
        int4 sc = *(const int4*)(bp + j + 8);
        int4 sd = *(const int4*)(bp + j + 12);
        u32 u0 = y1n[(size_t)sa.x * 64 + lane];
        u32 u1 = y1n[(size_t)sa.y * 64 + lane];
        u32 u2 = y1n[(size_t)sa.z * 64 + lane];
        u32 u3 = y1n[(size_t)sa.w * 64 + lane];
        u32 u4 = y1n[(size_t)sb.x * 64 + lane];
        u32 u5 = y1n[(size_t)sb.y * 64 + lane];
        u32 u6 = y1n[(size_t)sb.z * 64 + lane];
        u32 u7 = y1n[(size_t)sb.w * 64 + lane];
        u32 u8 = y1n[(size_t)sc.x * 64 + lane];
        u32 u9 = y1n[(size_t)sc.y * 64 + lane];
        u32 ua = y1n[(size_t)sc.z * 64 + lane];
        u32 ub = y1n[(size_t)sc.w * 64 + lane];
        u32 uc = y1n[(size_t)sd.x * 64 + lane];
        u32 ud = y1n[(size_t)sd.y * 64 + lane];
        u32 ue = y1n[(size_t)sd.z * 64 + lane];
        u32 uf = y1n[(size_t)sd.w * 64 + lane];
        a0 += bflo(u0) + bflo(u1) + bflo(u2) + bflo(u3)
            + bflo(u4) + bflo(u5) + bflo(u6) + bflo(u7)
            + bflo(u8) + bflo(u9) + bflo(ua) + bflo(ub)
            + bflo(uc) + bflo(ud) + bflo(ue) + bflo(uf);
        a1 += bfhi(u0) + bfhi(u1) + bfhi(u2) + bfhi(u3)
            + bfhi(u4) + bfhi(u5) + bfhi(u6) + bfhi(u7)
            + bfhi(u8) + bfhi(u9) + bfhi(ua) + bfhi(ub)
            + bfhi(uc) + bfhi(ud) + bfhi(ue) + bfhi(uf);
    }
    if (j + 8 <= d) {
        int4 sa = *(const int4*)(bp + j);
        int4 sb = *(const int4*)(bp + j + 4);
        u32 u0 = y1n[(size_t)sa.x * 64 + lane];
        u32 u1 = y1n[(size_t)sa.y * 64 + lane];
        u32 u2 = y1n[(size_t)sa.z * 64 + lane];
        u32 u3 = y1n[(size_t)sa.w * 64 + lane];
        u32 u4 = y1n[(size_t)sb.x * 64 + lane];
        u32 u5 = y1n[(size_t)sb.y * 64 + lane];
        u32 u6 = y1n[(size_t)sb.z * 64 + lane];
        u32 u7 = y1n[(size_t)sb.w * 64 + lane];
        a0 += bflo(u0) + bflo(u1) + bflo(u2) + bflo(u3)
            + bflo(u4) + bflo(u5) + bflo(u6) + bflo(u7);
        a1 += bfhi(u0) + bfhi(u1) + bfhi(u2) + bfhi(u3)
            + bfhi(u4) + bfhi(u5) + bfhi(u6) + bfhi(u7);
        j += 8;
    }
    if (j + 4 <= d) {
        int4 s4 = *(const int4*)(bp + j);
        u32 u0 = y1n[(size_t)s4.x * 64 + lane];
        u32 u1 = y1n[(size_t)s4.y * 64 + lane];
        u32 u2 = y1n[(size_t)s4.z * 64 + lane];
        u32 u3 = y1n[(size_t)s4.w * 64 + lane];
        a0 += bflo(u0) + bflo(u1) + bflo(u2) + bflo(u3);
        a1 += bfhi(u0) + bfhi(u1) + bfhi(u2) + bfhi(u3);
        j += 4;
    }
    for (; j < d; ++j) {
        int s = bp[j];
        u32 u = y1n[(size_t)s * 64 + lane];
        a0 += bflo(u); a1 += bfhi(u);
    }
    float inv = 1.f / fmaxf((float)deg, 1.f);
    u32 ur = y1r[(size_t)n * 64 + lane];
    float2 bb = ((const float2*)b1)[lane];
    float v0 = fmaxf(a0 * inv + bflo(ur) + bb.x, 0.f);
    float v1 = fmaxf(a1 * inv + bfhi(ur) + bb.y, 0.f);
    h1[(size_t)n * 64 + lane] = packbf2(v0, v1);
}

// ---------------- agg2: out = mean_neigh(y2n) + y2r + b2 (fp32), MLP16 ------
__global__ __launch_bounds__(256) void agg2_kernel(const u32* __restrict__ y2n,
                                                   const u32* __restrict__ y2r,
                                                   const int* __restrict__ degI,
                                                   const int* __restrict__ bins,
                                                   const float* __restrict__ b2,
                                                   float2* __restrict__ out) {
    int w = threadIdx.x >> 6, lane = threadIdx.x & 63;
    int half = lane >> 5, dd = lane & 31;
    int n = blockIdx.x * 4 + w;
    if (n >= N_NODES) return;
    int deg = degI[n];
    int d = min(deg, BINCAP);
    const int* bp = bins + n * BINCAP;
    float a0 = 0.f, a1 = 0.f;
    int j = 0;
    for (; j + 16 <= d; j += 16) {
        int s0 = bp[j + half],      s1 = bp[j + 2 + half];
        int s2 = bp[j + 4 + half],  s3 = bp[j + 6 + half];
        int s4 = bp[j + 8 + half],  s5 = bp[j + 10 + half];
        int s6 = bp[j + 12 + half], s7 = bp[j + 14 + half];
        u32 u0 = y2n[(size_t)s0 * 32 + dd];
        u32 u1 = y2n[(size_t)s1 * 32 + dd];
        u32 u2 = y2n[(size_t)s2 * 32 + dd];
        u32 u3 = y2n[(size_t)s3 * 32 + dd];
        u32 u4 = y2n[(size_t)s4 * 32 + dd];
        u32 u5 = y2n[(size_t)s5 * 32 + dd];
        u32 u6 = y2n[(size_t)s6 * 32 + dd];
        u32 u7 = y2n[(size_t)s7 * 32 + dd];
        a0 += bflo(u0) + bflo(u1) + bflo(u2) + bflo(u3)
            + bflo(u4) + bflo(u5) + bflo(u6) + bflo(u7);
        a1 += bfhi(u0) + bfhi(u1) + bfhi(u2) + bfhi(u3)
            + bfhi(u4) + bfhi(u5) + bfhi(u6) + bfhi(u7);
    }
    if (j + 8 <= d) {
        int s0 = bp[j + half],     s1 = bp[j + 2 + half];
        int s2 = bp[j + 4 + half], s3 = bp[j + 6 + half];
        u32 u0 = y2n[(size_t)s0 * 32 + dd];
        u32 u1 = y2n[(size_t)s1 * 32 + dd];
        u32 u2 = y2n[(size_t)s2 * 32 + dd];
        u32 u3 = y2n[(size_t)s3 * 32 + dd];
        a0 += bflo(u0) + bflo(u1) + bflo(u2) + bflo(u3);
        a1 += bfhi(u0) + bfhi(u1) + bfhi(u2) + bfhi(u3);
        j += 8;
    }
    if (j + 4 <= d) {
        int s0 = bp[j + half], s1 = bp[j + 2 + half];
        u32 u0 = y2n[(size_t)s0 * 32 + dd];
        u32 u1 = y2n[(size_t)s1 * 32 + dd];
        a0 += bflo(u0) + bflo(u1);
        a1 += bfhi(u0) + bfhi(u1);
        j += 4;
    }
    if (j + 2 <= d) {
        int s = bp[j + half];
        u32 u = y2n[(size_t)s * 32 + dd];
        a0 += bflo(u); a1 += bfhi(u);
        j += 2;
    }
    if (j < d && half == 0) {
        int s = bp[j];
        u32 u = y2n[(size_t)s * 32 + dd];
        a0 += bflo(u); a1 += bfhi(u);
    }
    a0 += __shfl_xor(a0, 32, 64);
    a1 += __shfl_xor(a1, 32, 64);
    if (half == 0) {
        float inv = 1.f / fmaxf((float)deg, 1.f);
        u32 ur = y2r[(size_t)n * 32 + dd];
        float2 bb = ((const float2*)b2)[dd];
        float2 o;
        o.x = a0 * inv + bflo(ur) + bb.x;
        o.y = a1 * inv + bfhi(ur) + bb.y;
        out[(size_t)n * 32 + dd] = o;
    }
}

// ---------------- launch ----------------

extern "C" void kernel_launch(void* const* d_in, const int* in_sizes, int n_in,
                              void* d_out, int out_size, void* d_ws, size_t ws_size,
                              hipStream_t stream) {
    const float* x   = (const float*)d_in[0];
    const int*   ei  = (const int*)d_in[1];
    const float* W1l = (const float*)d_in[2];
    const float* b1  = (const float*)d_in[3];
    const float* W1r = (const float*)d_in[4];
    const float* W2l = (const float*)d_in[5];
    const float* b2  = (const float*)d_in[6];
    const float* W2r = (const float*)d_in[7];

    char* wp = (char*)d_ws;
    auto alloc = [&](size_t bytes) -> char* {
        char* p = wp;
        wp += (bytes + 255) & ~(size_t)255;
        return p;
    };
    int* degI = (int*)alloc((size_t)N_NODES * 4);
    int* bins = (int*)alloc((size_t)N_NODES * BINCAP * 4);
    u32* wb1  = (u32*)alloc((size_t)WB1_CNT * 4);
    u32* wb2  = (u32*)alloc((size_t)WB2_CNT * 4);
    u32* y1n  = (u32*)alloc((size_t)MPAD * 64 * 4);   // [MPAD][128] bf16 (neighbor half)
    u32* y1r  = (u32*)alloc((size_t)MPAD * 64 * 4);   // [MPAD][128] bf16 (root half)
    u32* h1   = (u32*)alloc((size_t)MPAD * 64 * 4);   // [MPAD][128] bf16
    u32* y2n  = (u32*)alloc((size_t)MPAD * 32 * 4);   // [MPAD][64] bf16
    u32* y2r  = (u32*)alloc((size_t)MPAD * 32 * 4);

    prep_w_kernel<<<(PREP_TOT + 255) / 256, 256, 0, stream>>>(
        W1l, W1r, W2l, W2r, wb1, wb2, degI);
    gemm1_fused_kernel<<<G1_GEMM_BLOCKS + G1_EDGE_BLOCKS, 256, 0, stream>>>(
        x, (const ushort*)wb1, (ushort*)y1n, (ushort*)y1r, ei, degI, bins);
    agg1_kernel<<<(N_NODES + 3) / 4, 256, 0, stream>>>(
        y1n, y1r, degI, bins, b1, h1);
    gemm2_kernel<<<392, 256, 0, stream>>>(
        (const ushort*)h1, (const ushort*)wb2, (ushort*)y2n, (ushort*)y2r);
    agg2_kernel<<<(N_NODES + 3) / 4, 256, 0, stream>>>(
        y2n, y2r, degI, bins, b2, (float2*)d_out);
}